// Round 11
// baseline (215.254 us; speedup 1.0000x reference)
//
#include <hip/hip_runtime.h>
#include <hip/hip_bf16.h>

constexpr int NN = 100000;
constexpr int NE = 625000;
constexpr int F  = 128;
constexpr int C  = 32;
constexpr int CQ  = C / 4;  // 8 float4 per projected row
constexpr int NB  = (NN + 255) / 256;   // 391 scan blocks

// ---------- degree / norm ----------
__global__ void k_zero(int* __restrict__ cnt) {
    int i = blockIdx.x * blockDim.x + threadIdx.x;
    if (i < NN) cnt[i] = 0;
}

__global__ void k_count(const int* __restrict__ dstA, int* __restrict__ cnt) {
    int e = blockIdx.x * blockDim.x + threadIdx.x;
    if (e < NE) atomicAdd(&cnt[dstA[e]], 1);
}

__global__ void k_dinv(const int* __restrict__ cnt, float* __restrict__ dinv) {
    int i = blockIdx.x * blockDim.x + threadIdx.x;
    if (i < NN) dinv[i] = rsqrtf((float)(cnt[i] + 1));   // +1 self loop
}

// ---------- CSR build: two-level scan ----------
__global__ __launch_bounds__(256) void k_blocksum(const int* __restrict__ cnt,
                                                  int* __restrict__ blocksums) {
    int idx = blockIdx.x * 256 + threadIdx.x;
    int v = (idx < NN) ? cnt[idx] : 0;
    #pragma unroll
    for (int off = 32; off; off >>= 1) v += __shfl_down(v, off, 64);
    __shared__ int ws[4];
    int lane = threadIdx.x & 63, wid = threadIdx.x >> 6;
    if (lane == 0) ws[wid] = v;
    __syncthreads();
    if (threadIdx.x == 0)
        blocksums[blockIdx.x] = ws[0] + ws[1] + ws[2] + ws[3];
}

__global__ __launch_bounds__(512) void k_scanB(const int* __restrict__ blocksums,
                                               int* __restrict__ blockoff,
                                               int* __restrict__ rowptr) {
    __shared__ int s[512];
    int t = threadIdx.x;
    s[t] = (t < NB) ? blocksums[t] : 0;
    __syncthreads();
    for (int off = 1; off < 512; off <<= 1) {
        int v = (t >= off) ? s[t - off] : 0;
        __syncthreads();
        s[t] += v;
        __syncthreads();
    }
    if (t < NB) blockoff[t] = (t == 0) ? 0 : s[t - 1];
    if (t == NB - 1) rowptr[NN] = s[t];
}

__global__ __launch_bounds__(256) void k_scanC(const int* __restrict__ cnt,
                                               const int* __restrict__ blockoff,
                                               int* __restrict__ rowptr,
                                               int* __restrict__ cursor) {
    __shared__ int s[256];
    int t = threadIdx.x;
    int idx = blockIdx.x * 256 + t;
    int val = (idx < NN) ? cnt[idx] : 0;
    s[t] = val;
    __syncthreads();
    for (int off = 1; off < 256; off <<= 1) {
        int v = (t >= off) ? s[t - off] : 0;
        __syncthreads();
        s[t] += v;
        __syncthreads();
    }
    if (idx < NN) {
        int r = blockoff[blockIdx.x] + s[t] - val;
        rowptr[idx] = r;
        cursor[idx] = r;
    }
}

__global__ void k_fill(const int* __restrict__ srcA, const int* __restrict__ dstA,
                       int* __restrict__ cursor, int* __restrict__ col) {
    int e = blockIdx.x * blockDim.x + threadIdx.x;
    if (e >= NE) return;
    int s = srcA[e], d = dstA[e];
    int pos = atomicAdd(&cursor[d], 1);
    col[pos] = s;
}

// ---------- projection + prescale: u0 = dinv ⊙ (x @ W^T) ----------
// thread per node. W read from GLOBAL with wave-uniform addresses (c,q are
// uniform loop counters; const __restrict__) -> backend promotes to s_load,
// FMAs take the W operand from SGPRs. No LDS, no syncthreads, no conflicts.
// #pragma unroll 4 caps live x-float4s at 4 -> ~60 VGPR, no spill.
__global__ __launch_bounds__(256) void k_proj(const float* __restrict__ x,
                                              const float* __restrict__ W,
                                              const float* __restrict__ dinv,
                                              float* __restrict__ u0) {
    int node = blockIdx.x * 256 + threadIdx.x;
    if (node >= NN) return;

    const float4* xr = (const float4*)(x + (size_t)node * F);
    const float4* W4 = (const float4*)W;     // [C][32] float4, uniform addr

    float acc[C];
    #pragma unroll
    for (int c = 0; c < C; ++c) acc[c] = 0.f;

    #pragma unroll 4
    for (int q = 0; q < F / 4; ++q) {
        float4 xv = xr[q];
        #pragma unroll
        for (int c = 0; c < C; ++c) {
            float4 w = W4[c * (F / 4) + q];   // wave-uniform -> scalar load
            acc[c] += xv.x * w.x + xv.y * w.y + xv.z * w.z + xv.w * w.w;
        }
    }

    float dn = dinv[node];
    float4* op = (float4*)(u0 + (size_t)node * C);
    #pragma unroll
    for (int q8 = 0; q8 < CQ; ++q8)
        op[q8] = make_float4(dn * acc[4*q8+0], dn * acc[4*q8+1],
                             dn * acc[4*q8+2], dn * acc[4*q8+3]);
}

// ---------- hop 1: u1[i] = dinv[i]^2 * (u0[i] + sum_e u0[col]) ----------
__global__ void k_gather(const float* __restrict__ uin, const int* __restrict__ rowptr,
                         const int* __restrict__ col, const float* __restrict__ dinv,
                         float* __restrict__ uout) {
    int t = blockIdx.x * blockDim.x + threadIdx.x;   // thread per (node, float4 chunk)
    if (t >= NN * CQ) return;
    int node = t >> 3;   // CQ = 8
    int q    = t & 7;
    float4 v = ((const float4*)uin)[node * CQ + q];  // self term
    float ax = v.x, ay = v.y, az = v.z, aw = v.w;
    int e0 = rowptr[node], e1 = rowptr[node + 1];
    for (int e = e0; e < e1; ++e) {
        int s = col[e];
        float4 u = ((const float4*)uin)[s * CQ + q];
        ax += u.x; ay += u.y; az += u.z; aw += u.w;
    }
    float dn = dinv[node];
    float c = dn * dn;
    ((float4*)uout)[node * CQ + q] = make_float4(c * ax, c * ay, c * az, c * aw);
}

// ---------- hop 2 + bias + log_softmax, thread = (node, class-quad of 8) ----------
// logits = dinv[i] * (u1[i] + sum_e u1[col]) + b
__global__ __launch_bounds__(256) void k_hop2_finish(const float* __restrict__ uin,
                                                     const int* __restrict__ rowptr,
                                                     const int* __restrict__ col,
                                                     const float* __restrict__ dinv,
                                                     const float* __restrict__ b,
                                                     float* __restrict__ out) {
    int t = blockIdx.x * 256 + threadIdx.x;
    if (t >= NN * 4) return;
    int node = t >> 2;
    int qr   = t & 3;          // classes [qr*8, qr*8+8)

    const float4* zrow = (const float4*)(uin + (size_t)node * C) + qr * 2;
    float4 a0 = zrow[0], a1 = zrow[1];            // self term

    int e0 = rowptr[node], e1 = rowptr[node + 1];
    for (int e = e0; e < e1; ++e) {
        int s = col[e];             // 4 lanes same address -> broadcast
        const float4* u = (const float4*)(uin + (size_t)s * C) + qr * 2;
        float4 u0 = u[0], u1 = u[1];
        a0.x += u0.x; a0.y += u0.y; a0.z += u0.z; a0.w += u0.w;
        a1.x += u1.x; a1.y += u1.y; a1.z += u1.z; a1.w += u1.w;
    }

    float dn = dinv[node];
    float4 b0 = ((const float4*)b)[qr * 2];
    float4 b1 = ((const float4*)b)[qr * 2 + 1];
    float v[8] = { dn * a0.x + b0.x, dn * a0.y + b0.y, dn * a0.z + b0.z, dn * a0.w + b0.w,
                   dn * a1.x + b1.x, dn * a1.y + b1.y, dn * a1.z + b1.z, dn * a1.w + b1.w };

    float m = v[0];
    #pragma unroll
    for (int c = 1; c < 8; ++c) m = fmaxf(m, v[c]);
    m = fmaxf(m, __shfl_xor(m, 1, 64));     // reduce across the node's 4 lanes
    m = fmaxf(m, __shfl_xor(m, 2, 64));
    float s = 0.f;
    #pragma unroll
    for (int c = 0; c < 8; ++c) s += expf(v[c] - m);
    s += __shfl_xor(s, 1, 64);
    s += __shfl_xor(s, 2, 64);
    float lse = m + logf(s);

    float4* op = (float4*)(out + (size_t)node * C + qr * 8);
    op[0] = make_float4(v[0]-lse, v[1]-lse, v[2]-lse, v[3]-lse);
    op[1] = make_float4(v[4]-lse, v[5]-lse, v[6]-lse, v[7]-lse);
}

extern "C" void kernel_launch(void* const* d_in, const int* in_sizes, int n_in,
                              void* d_out, int out_size, void* d_ws, size_t ws_size,
                              hipStream_t stream) {
    const float* x  = (const float*)d_in[0];
    const int*   ei = (const int*)d_in[1];     // [2, NE] int32
    const float* W  = (const float*)d_in[2];
    const float* b  = (const float*)d_in[3];
    float* out = (float*)d_out;

    const int* srcA = ei;
    const int* dstA = ei + NE;

    char* p = (char*)d_ws;
    auto alloc = [&](size_t bytes) { char* r = p; p += (bytes + 255) & ~(size_t)255; return r; };
    int*   cnt       = (int*)  alloc(sizeof(int) * NN);
    float* dinv      = (float*)alloc(sizeof(float) * NN);
    int*   rowptr    = (int*)  alloc(sizeof(int) * (NN + 1));
    int*   cursor    = (int*)  alloc(sizeof(int) * NN);
    int*   blocksums = (int*)  alloc(sizeof(int) * NB);
    int*   blockoff  = (int*)  alloc(sizeof(int) * NB);
    int*   col       = (int*)  alloc(sizeof(int) * NE);
    float* u0        = (float*)alloc(sizeof(float) * (size_t)NN * C);
    float* u1        = (float*)alloc(sizeof(float) * (size_t)NN * C);

    // norm + CSR build
    k_zero    <<<(NN + 255) / 256, 256, 0, stream>>>(cnt);
    k_count   <<<(NE + 255) / 256, 256, 0, stream>>>(dstA, cnt);
    k_dinv    <<<(NN + 255) / 256, 256, 0, stream>>>(cnt, dinv);
    k_blocksum<<<NB, 256, 0, stream>>>(cnt, blocksums);
    k_scanB   <<<1, 512, 0, stream>>>(blocksums, blockoff, rowptr);
    k_scanC   <<<NB, 256, 0, stream>>>(cnt, blockoff, rowptr, cursor);
    k_fill    <<<(NE + 255) / 256, 256, 0, stream>>>(srcA, dstA, cursor, col);

    // projection + prescale: u0 = dinv ⊙ (x W^T)
    k_proj<<<(NN + 255) / 256, 256, 0, stream>>>(x, W, dinv, u0);

    // hop 1: u0 -> u1 (prescaled domain)
    k_gather<<<(NN * CQ + 255) / 256, 256, 0, stream>>>(u0, rowptr, col, dinv, u1);
    // hop 2 fused with bias + log_softmax: u1 -> out
    k_hop2_finish<<<(NN * 4 + 255) / 256, 256, 0, stream>>>(u1, rowptr, col, dinv, b, out);
}